// Round 16
// baseline (105.795 us; speedup 1.0000x reference)
//
#include <hip/hip_runtime.h>
#include <math.h>

#define C_   128
#define T_   64
#define V_   25
#define TV   1600       // T_*V_
#define CTV  204800     // C_*TV
#define EPS  1e-5f
#define TT   2          // t's per tile
#define HS   136        // hT/yT row stride (bf16), 272 B (16B-aligned)
#define ZS   72         // z row stride (bf16), 144 B (16B-aligned)

typedef __bf16 bf16x8 __attribute__((ext_vector_type(8)));
typedef __bf16 bf16x4 __attribute__((ext_vector_type(4)));
typedef float  f32x4  __attribute__((ext_vector_type(4)));

// GELU exact via A&S 7.1.25 erf approx (|eps|<=2.5e-5 in erf -> negligible vs bf16).
__device__ __forceinline__ float gelu_exact(float x) {
  float y = fabsf(x) * 0.70710678118654752440f;
  float t = __builtin_amdgcn_rcpf(fmaf(0.47047f, y, 1.0f));
  float p = fmaf(0.7478556f, t, -0.0958798f);
  p = fmaf(p, t, 0.3480242f);
  p = p * t;
  float s = p * __expf(-y * y);           // s ~= 1 - erf(y)
  float hxs = 0.5f * x * s;
  return x >= 0.0f ? x - hxs : hxs;
}

// Pack conv weights (BN0 folded into W1) + spatial matrices into MFMA frag order.
// Frag (A or B role, identical lane map): lane l, elem j -> M[row=l&15][k=(l>>4)*8+j]
__global__ __launch_bounds__(256) void prep_pack(
    const float* __restrict__ W1, const float* __restrict__ W2,
    const float* __restrict__ topo, const float* __restrict__ spat,
    const float* __restrict__ b1,
    const float* __restrict__ bn0g, const float* __restrict__ bn0b,
    const float* __restrict__ bn0m, const float* __restrict__ bn0v,
    const float* __restrict__ bn1g, const float* __restrict__ bn1b,
    const float* __restrict__ bn1m, const float* __restrict__ bn1v,
    const float* __restrict__ bn2g, const float* __restrict__ bn2b,
    const float* __restrict__ bn2m, const float* __restrict__ bn2v,
    __bf16* __restrict__ W1p, __bf16* __restrict__ W2p, __bf16* __restrict__ Sp,
    float* __restrict__ b1a, float* __restrict__ binv, float* __restrict__ badd) {
  if (blockIdx.x == 128) {   // scalar prep: b1a = b1 + W1*add0; BN1/BN2 folded params
    int o = threadIdx.x;     // 0..255
    float acc = b1[o];
    for (int c = 0; c < 128; ++c) {
      float inv = bn0g[c] * rsqrtf(bn0v[c] + EPS);
      float add = fmaf(-bn0m[c], inv, bn0b[c]);
      acc = fmaf(W1[o * 128 + c], add, acc);
    }
    b1a[o] = acc;
    float g, bb, m, vv;
    if (o < 128) { g = bn1g[o]; bb = bn1b[o]; m = bn1m[o]; vv = bn1v[o]; }
    else { int c = o - 128; g = bn2g[c]; bb = bn2b[c]; m = bn2m[c]; vv = bn2v[c]; }
    float inv = g * rsqrtf(vv + EPS);
    binv[o] = inv;
    badd[o] = fmaf(-m, inv, bb);
    return;
  }
  int i = blockIdx.x * 256 + threadIdx.x;
  if (i < 32768) {   // W1p: 16 ot * 4 ks * 64 * 8, scaled by inv0[c]
    int j = i & 7, l = (i >> 3) & 63, ks = (i >> 9) & 3, ot = i >> 11;
    int o = ot * 16 + (l & 15);
    int c = ks * 32 + ((l >> 4) << 3) + j;
    float inv = bn0g[c] * rsqrtf(bn0v[c] + EPS);
    W1p[i] = (__bf16)(W1[o * 128 + c] * inv);
  }
  if (i < 16384) {   // W2p: 8 ot * 4 ks * 64 * 8
    int j = i & 7, l = (i >> 3) & 63, ks = (i >> 9) & 3, ot = i >> 11;
    int o = ot * 16 + (l & 15);
    int c = ks * 32 + ((l >> 4) << 3) + j;
    W2p[i] = (__bf16)W2[o * 128 + c];
  }
  if (i < 8192) {    // Sp: h(2)*mat(1)*ut(1)*64*8, zero-padded u,v >= 25
    int j = i & 7, l = (i >> 3) & 63, ut = (i >> 9) & 1, mat = (i >> 10) & 1, h = i >> 11;
    int u = ut * 16 + (l & 15);
    int v = ((l >> 4) << 3) + j;
    const float* src = mat ? spat : topo;
    Sp[i] = (__bf16)((u < 25 && v < 25) ? src[h * 625 + u * 25 + v] : 0.0f);
  }
}

// ---------------- phase helpers (all __forceinline__) ----------------

__device__ __forceinline__ void p0_load(float xv[13], const float* xb, int tid) {
  const int c = tid >> 2, q = tid & 3;
  const int t = q & 1, vh = q >> 1;
  const float* xr = xb + c * TV + t * V_ + vh * 12;   // v0 = vh*12
  #pragma unroll
  for (int i = 0; i < 13; ++i) xv[i] = xr[i];
}

__device__ __forceinline__ void p0_write(__bf16* sA, const float xv[13], int tid) {
  const int c = tid >> 2, q = tid & 3;
  const int t = q & 1, vh = q >> 1;
  const int v0 = vh * 12;          // 0..12 / 12..24 (v=12 written twice, same value)
  #pragma unroll
  for (int i = 0; i < 13; ++i)
    sA[(t * 32 + v0 + i) * HS + c] = (__bf16)xv[i];
}

__device__ __forceinline__ void p0_stage(__bf16* sA, const float* xb, int tid) {
  float xv[13];
  p0_load(xv, xb, tid);
  p0_write(sA, xv, tid);
}

__device__ __forceinline__ void conv1_mfma(const __bf16* sA, const __bf16* W1p,
    int wave, int lane, int lr, int lg, float bv0, float bv1, f32x4 acc[2][4]) {
  #pragma unroll
  for (int mt = 0; mt < 4; ++mt) {
    acc[0][mt] = f32x4{bv0, bv0, bv0, bv0};
    acc[1][mt] = f32x4{bv1, bv1, bv1, bv1};
  }
  #pragma unroll
  for (int ks = 0; ks < 4; ++ks) {
    bf16x8 ah[4];
    #pragma unroll
    for (int mt = 0; mt < 4; ++mt)
      ah[mt] = *reinterpret_cast<const bf16x8*>(&sA[(mt * 16 + lr) * HS + ks * 32 + lg * 8]);
    #pragma unroll
    for (int nt = 0; nt < 2; ++nt) {
      bf16x8 bw = *reinterpret_cast<const bf16x8*>(W1p + (((wave * 2 + nt) * 4 + ks) << 9) + lane * 8);
      #pragma unroll
      for (int mt = 0; mt < 4; ++mt)
        acc[nt][mt] = __builtin_amdgcn_mfma_f32_16x16x32_bf16(ah[mt], bw, acc[nt][mt], 0, 0, 0);
    }
  }
}

__device__ __forceinline__ void gelu_epi(const f32x4 acc[2][4], __bf16* sB, __bf16* sA,
    int wave, int lg, int o0, float inv0, float add0, float inv1, float add1) {
  __bf16* zdst = (wave < 4) ? sB : sA;
  #pragma unroll
  for (int nt = 0; nt < 2; ++nt) {
    const float inv = nt ? inv1 : inv0;
    const float add = nt ? add1 : add0;
    const int orow = (o0 + nt * 16) & 127;
    #pragma unroll
    for (int mt = 0; mt < 4; ++mt) {
      bf16x4 pk;
      #pragma unroll
      for (int r = 0; r < 4; ++r) {
        int v = ((mt & 1) * 16) + lg * 4 + r;
        float z = fmaf(gelu_exact(acc[nt][mt][r]), inv, add);
        pk[r] = (v < V_) ? (__bf16)z : (__bf16)0.0f;   // pad cols zeroed for free
      }
      *reinterpret_cast<bf16x4*>(zdst + orow * ZS + mt * 16 + lg * 4) = pk;
    }
  }
}

__device__ __forceinline__ void spatial_mfma(const __bf16* sB, const __bf16* sA,
    const bf16x8 at0, const bf16x8 at1, const bf16x8 as0, const bf16x8 as1,
    int cbase, int lr, int lg, float yv[2][2][4]) {
  f32x4 accY[2][2] = {}, accA[2][2] = {};
  #pragma unroll
  for (int t = 0; t < 2; ++t) {
    bf16x8 az1 = *reinterpret_cast<const bf16x8*>(&sB[(cbase + lr) * ZS + t * 32 + lg * 8]);
    bf16x8 az2 = *reinterpret_cast<const bf16x8*>(&sA[(cbase + lr) * ZS + t * 32 + lg * 8]);
    accY[0][t] = __builtin_amdgcn_mfma_f32_16x16x32_bf16(az1, at0, accY[0][t], 0, 0, 0);
    accY[1][t] = __builtin_amdgcn_mfma_f32_16x16x32_bf16(az1, at1, accY[1][t], 0, 0, 0);
    accA[0][t] = __builtin_amdgcn_mfma_f32_16x16x32_bf16(az2, as0, accA[0][t], 0, 0, 0);
    accA[1][t] = __builtin_amdgcn_mfma_f32_16x16x32_bf16(az2, as1, accA[1][t], 0, 0, 0);
  }
  #pragma unroll
  for (int ut = 0; ut < 2; ++ut) {
    const int u = ut * 16 + lr;
    #pragma unroll
    for (int t = 0; t < 2; ++t)
      #pragma unroll
      for (int r = 0; r < 4; ++r) {
        const int c = cbase + lg * 4 + r;
        float z1u = (float)sB[c * ZS + t * 32 + u];   // z1 pad cols are 0
        // u>=25: accY=accA=0 (Sp pad rows) and z1u pad -> yv=0: pad rows auto-zero
        yv[ut][t][r] = fmaf(z1u, accA[ut][t][r], accY[ut][t][r]);
      }
  }
}

__device__ __forceinline__ void p2_store(const float yv[2][2][4], __bf16* sB,
    int cbase, int lr, int lg) {
  #pragma unroll
  for (int ut = 0; ut < 2; ++ut)
    #pragma unroll
    for (int t = 0; t < 2; ++t) {
      const int row = t * 32 + ut * 16 + lr;
      bf16x4 pk;
      #pragma unroll
      for (int r = 0; r < 4; ++r) pk[r] = (__bf16)yv[ut][t][r];
      *reinterpret_cast<bf16x4*>(sB + row * HS + cbase + lg * 4) = pk;
    }
}

// conv2 in v4 orientation (A=W2 frag, B=yT rows): D col = (t,u), row = o-within-16.
__device__ __forceinline__ void conv2_mfma(const __bf16* sB, const __bf16* W2p,
    int wave, int lane, int lr, int lg, const f32x4 bv2q, f32x4 acc2[4]) {
  #pragma unroll
  for (int n4 = 0; n4 < 4; ++n4) acc2[n4] = bv2q;   // acc2[n4][r]: o = wave*16+lg*4+r
  #pragma unroll
  for (int ks = 0; ks < 4; ++ks) {
    bf16x8 af = *reinterpret_cast<const bf16x8*>(W2p + ((wave * 4 + ks) << 9) + lane * 8);
    #pragma unroll
    for (int n4 = 0; n4 < 4; ++n4) {
      bf16x8 ay = *reinterpret_cast<const bf16x8*>(&sB[(n4 * 16 + lr) * HS + ks * 32 + lg * 8]);
      acc2[n4] = __builtin_amdgcn_mfma_f32_16x16x32_bf16(af, ay, acc2[n4], 0, 0, 0);
    }
  }
}

__device__ __forceinline__ void p3_store(const f32x4 acc2[4], const float* xb,
    float* ob, int wave, int lr, int lg) {
  #pragma unroll
  for (int n4 = 0; n4 < 4; ++n4) {
    const int col = n4 * 16 + lr;
    const int t = col >> 5, u = col & 31;
    if (u < V_) {
      #pragma unroll
      for (int r = 0; r < 4; ++r) {
        const int o = wave * 16 + lg * 4 + r;
        const int off = o * TV + t * V_ + u;
        ob[off] = fmaxf(acc2[n4][r] + xb[off], 0.0f);   // u-contiguous across lr
      }
    }
  }
}

__global__ __launch_bounds__(512, 4) void fused_v15(
    const float* __restrict__ x, const float* __restrict__ b2,
    const __bf16* __restrict__ W1p, const __bf16* __restrict__ W2p,
    const __bf16* __restrict__ Sp,
    const float* __restrict__ b1a, const float* __restrict__ binv,
    const float* __restrict__ badd,
    float* __restrict__ out) {
  // Region A: hT (64 x HS) -> z2 (128 x ZS) -> hT' -> z2' . Region B: z1 -> yT -> z1' -> yT'.
  __shared__ __bf16 sA[9216];   // 18432 B
  __shared__ __bf16 sB[9216];   // 18432 B -> total 36864 B

  // XCD-aware bijective swizzle (2048 % 8 == 0): consecutive logical pb (same b,
  // adjacent t-groups, sharing straddled 64B output lines) land on the SAME XCD's
  // L2, so partial writes merge before HBM writeback. Round 14: FETCH 137->106 MB.
  const int hw = blockIdx.x;                // hardware index: XCD = hw % 8
  const int pb = (hw & 7) * 256 + (hw >> 3);// logical index: 0..2047
  const int b  = pb >> 4;
  const int tb0 = (pb & 15) * 2;
  const float* xb0 = x   + (size_t)b * CTV + tb0 * (TT * V_);
  float*       ob0 = out + (size_t)b * CTV + tb0 * (TT * V_);
  const float* xb1 = xb0 + TT * V_;
  float*       ob1 = ob0 + TT * V_;
  const int tid  = threadIdx.x;
  const int wave = tid >> 6, lane = tid & 63;
  const int lr = lane & 15, lg = lane >> 4;

  // -------- prefetch per-lane constants & spatial frags (latency hides under P0) --------
  const int o0 = wave * 32 + lr;        // conv1 output channel, nt=0 (nt=1 -> +16)
  const float bv1a0 = b1a[o0], bv1a1 = b1a[o0 + 16];
  const float inv0 = binv[o0], add0 = badd[o0];
  const float inv1 = binv[o0 + 16], add1 = badd[o0 + 16];
  const f32x4 bv2q = *reinterpret_cast<const f32x4*>(b2 + wave * 16 + lg * 4);
  const int h2 = wave >> 1, ch = wave & 1;
  const int cbase = h2 * 32 + ch * 16;
  const bf16x8 at0 = *reinterpret_cast<const bf16x8*>(Sp + (((h2 * 2 + 0) * 2 + 0) << 9) + lane * 8);
  const bf16x8 at1 = *reinterpret_cast<const bf16x8*>(Sp + (((h2 * 2 + 0) * 2 + 1) << 9) + lane * 8);
  const bf16x8 as0 = *reinterpret_cast<const bf16x8*>(Sp + (((h2 * 2 + 1) * 2 + 0) << 9) + lane * 8);
  const bf16x8 as1 = *reinterpret_cast<const bf16x8*>(Sp + (((h2 * 2 + 1) * 2 + 1) << 9) + lane * 8);

  f32x4 acc[2][4];     // conv1 accumulators
  f32x4 acc2[4];       // conv2 accumulators
  float yv[2][2][4];

  // ================ TILE 0 ================
  p0_stage(sA, xb0, tid);
  __syncthreads();   // (1)

  conv1_mfma(sA, W1p, wave, lane, lr, lg, bv1a0, bv1a1, acc);
  __syncthreads();   // (2) hT reads done; sA -> z2

  gelu_epi(acc, sB, sA, wave, lg, o0, inv0, add0, inv1, add1);
  __syncthreads();   // (3)

  // T14 async-stage split: ISSUE tile1's x loads now — their HBM/L2 latency
  // hides under the spatial phase's MFMAs; ds_writes land after barrier (4).
  float xv1[13];
  p0_load(xv1, xb1, tid);

  spatial_mfma(sB, sA, at0, at1, as0, as1, cbase, lr, lg, yv);
  __syncthreads();   // (4) z reads done; sA free, sB -> yT

  p0_write(sA, xv1, tid);        // write prefetched tile1 x (loads already landed)
  p2_store(yv, sB, cbase, lr, lg);
  __syncthreads();   // (5) yT + hT' both visible

  // -------- barrier-free stretch: conv2(T0) + conv1(T1) + store(T0) --------
  conv2_mfma(sB, W2p, wave, lane, lr, lg, bv2q, acc2);       // reads sB
  conv1_mfma(sA, W1p, wave, lane, lr, lg, bv1a0, bv1a1, acc); // reads sA
  p3_store(acc2, xb0, ob0, wave, lr, lg);                     // global out, hides under MFMA
  __syncthreads();   // (2') yT reads done; sB -> z1', sA -> z2'

  // ================ TILE 1 ================
  gelu_epi(acc, sB, sA, wave, lg, o0, inv0, add0, inv1, add1);
  __syncthreads();   // (3')

  spatial_mfma(sB, sA, at0, at1, as0, as1, cbase, lr, lg, yv);
  __syncthreads();   // (4')

  p2_store(yv, sB, cbase, lr, lg);
  __syncthreads();   // (5')

  conv2_mfma(sB, W2p, wave, lane, lr, lg, bv2q, acc2);
  p3_store(acc2, xb1, ob1, wave, lr, lg);
}

extern "C" void kernel_launch(void* const* d_in, const int* in_sizes, int n_in,
                              void* d_out, int out_size, void* d_ws, size_t ws_size,
                              hipStream_t stream) {
  const float* x    = (const float*)d_in[0];
  const float* bn0g = (const float*)d_in[1];
  const float* bn0b = (const float*)d_in[2];
  const float* bn0m = (const float*)d_in[3];
  const float* bn0v = (const float*)d_in[4];
  const float* W1   = (const float*)d_in[5];
  const float* b1   = (const float*)d_in[6];
  const float* bn1g = (const float*)d_in[7];
  const float* bn1b = (const float*)d_in[8];
  const float* bn1m = (const float*)d_in[9];
  const float* bn1v = (const float*)d_in[10];
  const float* bn2g = (const float*)d_in[11];
  const float* bn2b = (const float*)d_in[12];
  const float* bn2m = (const float*)d_in[13];
  const float* bn2v = (const float*)d_in[14];
  const float* topo = (const float*)d_in[15];
  const float* spat = (const float*)d_in[16];
  const float* W2   = (const float*)d_in[17];
  const float* b2   = (const float*)d_in[18];
  float* out = (float*)d_out;

  __bf16* W1p = (__bf16*)d_ws;                    // 32768 elems (65536 B)
  __bf16* W2p = W1p + 32768;                      // 16384 elems (32768 B)
  __bf16* Sp  = W2p + 16384;                      //  8192 elems (16384 B)
  float*  b1a  = (float*)((char*)d_ws + 114688);  // 256 f32
  float*  binv = b1a + 256;                       // 256 f32
  float*  badd = binv + 256;                      // 256 f32

  prep_pack<<<129, 256, 0, stream>>>(W1, W2, topo, spat, b1,
                                     bn0g, bn0b, bn0m, bn0v,
                                     bn1g, bn1b, bn1m, bn1v,
                                     bn2g, bn2b, bn2m, bn2v,
                                     W1p, W2p, Sp, b1a, binv, badd);
  fused_v15<<<2048, 512, 0, stream>>>(
      x, b2, W1p, W2p, Sp, b1a, binv, badd, out);
}

// Round 17
// 99.413 us; speedup vs baseline: 1.0642x; 1.0642x over previous
//
#include <hip/hip_runtime.h>
#include <math.h>

#define C_   128
#define T_   64
#define V_   25
#define TV   1600       // T_*V_
#define CTV  204800     // C_*TV
#define EPS  1e-5f
#define TT   2          // t's per tile
#define HS   136        // hT/yT row stride (bf16), 272 B (16B-aligned)
#define ZS   72         // z row stride (bf16), 144 B (16B-aligned)
#define RSZ  9216       // region size (bf16 elems): fits z (128*72) and hT/yT (64*136)

typedef __bf16 bf16x8 __attribute__((ext_vector_type(8)));
typedef __bf16 bf16x4 __attribute__((ext_vector_type(4)));
typedef float  f32x4  __attribute__((ext_vector_type(4)));

// GELU exact via A&S 7.1.25 erf approx (|eps|<=2.5e-5 in erf -> negligible vs bf16).
__device__ __forceinline__ float gelu_exact(float x) {
  float y = fabsf(x) * 0.70710678118654752440f;
  float t = __builtin_amdgcn_rcpf(fmaf(0.47047f, y, 1.0f));
  float p = fmaf(0.7478556f, t, -0.0958798f);
  p = fmaf(p, t, 0.3480242f);
  p = p * t;
  float s = p * __expf(-y * y);           // s ~= 1 - erf(y)
  float hxs = 0.5f * x * s;
  return x >= 0.0f ? x - hxs : hxs;
}

// Pack conv weights (BN0 folded into W1) + spatial matrices into MFMA frag order.
// Frag (A or B role, identical lane map): lane l, elem j -> M[row=l&15][k=(l>>4)*8+j]
__global__ __launch_bounds__(256) void prep_pack(
    const float* __restrict__ W1, const float* __restrict__ W2,
    const float* __restrict__ topo, const float* __restrict__ spat,
    const float* __restrict__ b1,
    const float* __restrict__ bn0g, const float* __restrict__ bn0b,
    const float* __restrict__ bn0m, const float* __restrict__ bn0v,
    const float* __restrict__ bn1g, const float* __restrict__ bn1b,
    const float* __restrict__ bn1m, const float* __restrict__ bn1v,
    const float* __restrict__ bn2g, const float* __restrict__ bn2b,
    const float* __restrict__ bn2m, const float* __restrict__ bn2v,
    __bf16* __restrict__ W1p, __bf16* __restrict__ W2p, __bf16* __restrict__ Sp,
    float* __restrict__ b1a, float* __restrict__ binv, float* __restrict__ badd) {
  if (blockIdx.x == 128) {   // scalar prep: b1a = b1 + W1*add0; BN1/BN2 folded params
    int o = threadIdx.x;     // 0..255
    float acc = b1[o];
    for (int c = 0; c < 128; ++c) {
      float inv = bn0g[c] * rsqrtf(bn0v[c] + EPS);
      float add = fmaf(-bn0m[c], inv, bn0b[c]);
      acc = fmaf(W1[o * 128 + c], add, acc);
    }
    b1a[o] = acc;
    float g, bb, m, vv;
    if (o < 128) { g = bn1g[o]; bb = bn1b[o]; m = bn1m[o]; vv = bn1v[o]; }
    else { int c = o - 128; g = bn2g[c]; bb = bn2b[c]; m = bn2m[c]; vv = bn2v[c]; }
    float inv = g * rsqrtf(vv + EPS);
    binv[o] = inv;
    badd[o] = fmaf(-m, inv, bb);
    return;
  }
  int i = blockIdx.x * 256 + threadIdx.x;
  if (i < 32768) {   // W1p: 16 ot * 4 ks * 64 * 8, scaled by inv0[c]
    int j = i & 7, l = (i >> 3) & 63, ks = (i >> 9) & 3, ot = i >> 11;
    int o = ot * 16 + (l & 15);
    int c = ks * 32 + ((l >> 4) << 3) + j;
    float inv = bn0g[c] * rsqrtf(bn0v[c] + EPS);
    W1p[i] = (__bf16)(W1[o * 128 + c] * inv);
  }
  if (i < 16384) {   // W2p: 8 ot * 4 ks * 64 * 8
    int j = i & 7, l = (i >> 3) & 63, ks = (i >> 9) & 3, ot = i >> 11;
    int o = ot * 16 + (l & 15);
    int c = ks * 32 + ((l >> 4) << 3) + j;
    W2p[i] = (__bf16)W2[o * 128 + c];
  }
  if (i < 8192) {    // Sp: h(2)*mat(1)*ut(1)*64*8, zero-padded u,v >= 25
    int j = i & 7, l = (i >> 3) & 63, ut = (i >> 9) & 1, mat = (i >> 10) & 1, h = i >> 11;
    int u = ut * 16 + (l & 15);
    int v = ((l >> 4) << 3) + j;
    const float* src = mat ? spat : topo;
    Sp[i] = (__bf16)((u < 25 && v < 25) ? src[h * 625 + u * 25 + v] : 0.0f);
  }
}

// ---------------- phase helpers (all __forceinline__) ----------------

__device__ __forceinline__ void p0_stage(__bf16* hT, const float* xb, int tid) {
  const int c = tid >> 2, q = tid & 3;
  const int t = q & 1, vh = q >> 1;
  const float* xr = xb + c * TV + t * V_;
  const int v0 = vh * 12;          // 0..12 / 12..24 (v=12 written twice, same value)
  float xv[13];
  #pragma unroll
  for (int i = 0; i < 13; ++i) xv[i] = xr[v0 + i];
  #pragma unroll
  for (int i = 0; i < 13; ++i)
    hT[(t * 32 + v0 + i) * HS + c] = (__bf16)xv[i];
}

__device__ __forceinline__ void conv1_mfma(const __bf16* hT, const __bf16* W1p,
    int wave, int lane, int lr, int lg, float bv0, float bv1, f32x4 acc[2][4]) {
  #pragma unroll
  for (int mt = 0; mt < 4; ++mt) {
    acc[0][mt] = f32x4{bv0, bv0, bv0, bv0};
    acc[1][mt] = f32x4{bv1, bv1, bv1, bv1};
  }
  #pragma unroll
  for (int ks = 0; ks < 4; ++ks) {
    bf16x8 ah[4];
    #pragma unroll
    for (int mt = 0; mt < 4; ++mt)
      ah[mt] = *reinterpret_cast<const bf16x8*>(&hT[(mt * 16 + lr) * HS + ks * 32 + lg * 8]);
    #pragma unroll
    for (int nt = 0; nt < 2; ++nt) {
      bf16x8 bw = *reinterpret_cast<const bf16x8*>(W1p + (((wave * 2 + nt) * 4 + ks) << 9) + lane * 8);
      #pragma unroll
      for (int mt = 0; mt < 4; ++mt)
        acc[nt][mt] = __builtin_amdgcn_mfma_f32_16x16x32_bf16(ah[mt], bw, acc[nt][mt], 0, 0, 0);
    }
  }
}

__device__ __forceinline__ void gelu_epi(const f32x4 acc[2][4], __bf16* z1, __bf16* z2,
    int wave, int lg, int o0, float inv0, float add0, float inv1, float add1) {
  __bf16* zdst = (wave < 4) ? z1 : z2;
  #pragma unroll
  for (int nt = 0; nt < 2; ++nt) {
    const float inv = nt ? inv1 : inv0;
    const float add = nt ? add1 : add0;
    const int orow = (o0 + nt * 16) & 127;
    #pragma unroll
    for (int mt = 0; mt < 4; ++mt) {
      bf16x4 pk;
      #pragma unroll
      for (int r = 0; r < 4; ++r) {
        int v = ((mt & 1) * 16) + lg * 4 + r;
        float z = fmaf(gelu_exact(acc[nt][mt][r]), inv, add);
        pk[r] = (v < V_) ? (__bf16)z : (__bf16)0.0f;   // pad cols zeroed for free
      }
      *reinterpret_cast<bf16x4*>(zdst + orow * ZS + mt * 16 + lg * 4) = pk;
    }
  }
}

__device__ __forceinline__ void spatial_mfma(const __bf16* z1, const __bf16* z2,
    const bf16x8 at0, const bf16x8 at1, const bf16x8 as0, const bf16x8 as1,
    int cbase, int lr, int lg, float yv[2][2][4]) {
  f32x4 accY[2][2] = {}, accA[2][2] = {};
  #pragma unroll
  for (int t = 0; t < 2; ++t) {
    bf16x8 az1 = *reinterpret_cast<const bf16x8*>(&z1[(cbase + lr) * ZS + t * 32 + lg * 8]);
    bf16x8 az2 = *reinterpret_cast<const bf16x8*>(&z2[(cbase + lr) * ZS + t * 32 + lg * 8]);
    accY[0][t] = __builtin_amdgcn_mfma_f32_16x16x32_bf16(az1, at0, accY[0][t], 0, 0, 0);
    accY[1][t] = __builtin_amdgcn_mfma_f32_16x16x32_bf16(az1, at1, accY[1][t], 0, 0, 0);
    accA[0][t] = __builtin_amdgcn_mfma_f32_16x16x32_bf16(az2, as0, accA[0][t], 0, 0, 0);
    accA[1][t] = __builtin_amdgcn_mfma_f32_16x16x32_bf16(az2, as1, accA[1][t], 0, 0, 0);
  }
  #pragma unroll
  for (int ut = 0; ut < 2; ++ut) {
    const int u = ut * 16 + lr;
    #pragma unroll
    for (int t = 0; t < 2; ++t)
      #pragma unroll
      for (int r = 0; r < 4; ++r) {
        const int c = cbase + lg * 4 + r;
        float z1u = (float)z1[c * ZS + t * 32 + u];   // z1 pad cols are 0
        // u>=25: accY=accA=0 (Sp pad rows) and z1u pad -> yv=0: pad rows auto-zero
        yv[ut][t][r] = fmaf(z1u, accA[ut][t][r], accY[ut][t][r]);
      }
  }
}

__device__ __forceinline__ void p2_store(const float yv[2][2][4], __bf16* yT,
    int cbase, int lr, int lg) {
  #pragma unroll
  for (int ut = 0; ut < 2; ++ut)
    #pragma unroll
    for (int t = 0; t < 2; ++t) {
      const int row = t * 32 + ut * 16 + lr;
      bf16x4 pk;
      #pragma unroll
      for (int r = 0; r < 4; ++r) pk[r] = (__bf16)yv[ut][t][r];
      *reinterpret_cast<bf16x4*>(yT + row * HS + cbase + lg * 4) = pk;
    }
}

// conv2 in v4 orientation (A=W2 frag, B=yT rows): D col = (t,u), row = o-within-16.
__device__ __forceinline__ void conv2_mfma(const __bf16* yT, const __bf16* W2p,
    int wave, int lane, int lr, int lg, const f32x4 bv2q, f32x4 acc2[4]) {
  #pragma unroll
  for (int n4 = 0; n4 < 4; ++n4) acc2[n4] = bv2q;   // acc2[n4][r]: o = wave*16+lg*4+r
  #pragma unroll
  for (int ks = 0; ks < 4; ++ks) {
    bf16x8 af = *reinterpret_cast<const bf16x8*>(W2p + ((wave * 4 + ks) << 9) + lane * 8);
    #pragma unroll
    for (int n4 = 0; n4 < 4; ++n4) {
      bf16x8 ay = *reinterpret_cast<const bf16x8*>(&yT[(n4 * 16 + lr) * HS + ks * 32 + lg * 8]);
      acc2[n4] = __builtin_amdgcn_mfma_f32_16x16x32_bf16(af, ay, acc2[n4], 0, 0, 0);
    }
  }
}

__device__ __forceinline__ void p3_store(const f32x4 acc2[4], const float* xb,
    float* ob, int wave, int lr, int lg) {
  #pragma unroll
  for (int n4 = 0; n4 < 4; ++n4) {
    const int col = n4 * 16 + lr;
    const int t = col >> 5, u = col & 31;
    if (u < V_) {
      #pragma unroll
      for (int r = 0; r < 4; ++r) {
        const int o = wave * 16 + lg * 4 + r;
        const int off = o * TV + t * V_ + u;
        ob[off] = fmaxf(acc2[n4][r] + xb[off], 0.0f);   // u-contiguous across lr
      }
    }
  }
}

__global__ __launch_bounds__(512, 4) void fused_v16(
    const float* __restrict__ x, const float* __restrict__ b2,
    const __bf16* __restrict__ W1p, const __bf16* __restrict__ W2p,
    const __bf16* __restrict__ Sp,
    const float* __restrict__ b1a, const float* __restrict__ binv,
    const float* __restrict__ badd,
    float* __restrict__ out) {
  // Four dedicated regions (occupancy is register-bound at 2 blocks/CU, so 72 KB is free):
  // RA: hT (tile i), RB: yT, RC: z1, RD: z2. Dedicated z-regions delete 4 of v14's 9 barriers.
  __shared__ __bf16 sR[4 * RSZ];   // 73728 B
  __bf16* RA = sR;
  __bf16* RB = sR + RSZ;
  __bf16* RC = sR + 2 * RSZ;
  __bf16* RD = sR + 3 * RSZ;

  // XCD-aware bijective swizzle (2048 % 8 == 0): consecutive logical pb share straddled
  // 64B output lines -> same XCD L2 merges them (round 14: FETCH 137->106 MB).
  const int hw = blockIdx.x;                // hardware index: XCD = hw % 8
  const int pb = (hw & 7) * 256 + (hw >> 3);// logical index: 0..2047
  const int b  = pb >> 4;
  const int tb0 = (pb & 15) * 2;
  const float* xb0 = x   + (size_t)b * CTV + tb0 * (TT * V_);
  float*       ob0 = out + (size_t)b * CTV + tb0 * (TT * V_);
  const float* xb1 = xb0 + TT * V_;
  float*       ob1 = ob0 + TT * V_;
  const int tid  = threadIdx.x;
  const int wave = tid >> 6, lane = tid & 63;
  const int lr = lane & 15, lg = lane >> 4;

  // -------- prefetch per-lane constants & spatial frags (latency hides under P0) --------
  const int o0 = wave * 32 + lr;        // conv1 output channel, nt=0 (nt=1 -> +16)
  const float bv1a0 = b1a[o0], bv1a1 = b1a[o0 + 16];
  const float inv0 = binv[o0], add0 = badd[o0];
  const float inv1 = binv[o0 + 16], add1 = badd[o0 + 16];
  const f32x4 bv2q = *reinterpret_cast<const f32x4*>(b2 + wave * 16 + lg * 4);
  const int h2 = wave >> 1, ch = wave & 1;
  const int cbase = h2 * 32 + ch * 16;
  const bf16x8 at0 = *reinterpret_cast<const bf16x8*>(Sp + (((h2 * 2 + 0) * 2 + 0) << 9) + lane * 8);
  const bf16x8 at1 = *reinterpret_cast<const bf16x8*>(Sp + (((h2 * 2 + 0) * 2 + 1) << 9) + lane * 8);
  const bf16x8 as0 = *reinterpret_cast<const bf16x8*>(Sp + (((h2 * 2 + 1) * 2 + 0) << 9) + lane * 8);
  const bf16x8 as1 = *reinterpret_cast<const bf16x8*>(Sp + (((h2 * 2 + 1) * 2 + 1) << 9) + lane * 8);

  f32x4 acc[2][4];     // conv1 accumulators
  f32x4 acc2[4];       // conv2 accumulators
  float yv[2][2][4];

  // -------- prologue --------
  p0_stage(RA, xb0, tid);                // hT0 -> RA
  __syncthreads();   // (1) hT0 ready

  // -------- phase: conv1(T0) + gelu -> RC/RD (no WAR: z has its own regions) --------
  conv1_mfma(RA, W1p, wave, lane, lr, lg, bv1a0, bv1a1, acc);
  gelu_epi(acc, RC, RD, wave, lg, o0, inv0, add0, inv1, add1);
  __syncthreads();   // (2) z ready; RA (hT0) reads done

  // -------- phase: spatial(T0) + yT->RB + stage hT1->RA --------
  spatial_mfma(RC, RD, at0, at1, as0, as1, cbase, lr, lg, yv);
  p0_stage(RA, xb1, tid);                // RA free (conv1 reads drained at bar 2)
  p2_store(yv, RB, cbase, lr, lg);
  __syncthreads();   // (3) yT0 + hT1 visible; RC/RD reads done

  // -------- heavy phase: conv2(T0) + conv1(T1) + gelu(T1) + store(T0) --------
  conv2_mfma(RB, W2p, wave, lane, lr, lg, bv2q, acc2);        // reads RB
  conv1_mfma(RA, W1p, wave, lane, lr, lg, bv1a0, bv1a1, acc); // reads RA
  gelu_epi(acc, RC, RD, wave, lg, o0, inv0, add0, inv1, add1);// RC/RD free since bar 3
  p3_store(acc2, xb0, ob0, wave, lr, lg);                     // hides under MFMA
  __syncthreads();   // (4) z' ready; RB (yT0) reads done

  // -------- phase: spatial(T1) + yT'->RB --------
  spatial_mfma(RC, RD, at0, at1, as0, as1, cbase, lr, lg, yv);
  p2_store(yv, RB, cbase, lr, lg);
  __syncthreads();   // (5) yT1 visible

  // -------- epilogue: conv2(T1) + store(T1) --------
  conv2_mfma(RB, W2p, wave, lane, lr, lg, bv2q, acc2);
  p3_store(acc2, xb1, ob1, wave, lr, lg);
}

extern "C" void kernel_launch(void* const* d_in, const int* in_sizes, int n_in,
                              void* d_out, int out_size, void* d_ws, size_t ws_size,
                              hipStream_t stream) {
  const float* x    = (const float*)d_in[0];
  const float* bn0g = (const float*)d_in[1];
  const float* bn0b = (const float*)d_in[2];
  const float* bn0m = (const float*)d_in[3];
  const float* bn0v = (const float*)d_in[4];
  const float* W1   = (const float*)d_in[5];
  const float* b1   = (const float*)d_in[6];
  const float* bn1g = (const float*)d_in[7];
  const float* bn1b = (const float*)d_in[8];
  const float* bn1m = (const float*)d_in[9];
  const float* bn1v = (const float*)d_in[10];
  const float* bn2g = (const float*)d_in[11];
  const float* bn2b = (const float*)d_in[12];
  const float* bn2m = (const float*)d_in[13];
  const float* bn2v = (const float*)d_in[14];
  const float* topo = (const float*)d_in[15];
  const float* spat = (const float*)d_in[16];
  const float* W2   = (const float*)d_in[17];
  const float* b2   = (const float*)d_in[18];
  float* out = (float*)d_out;

  __bf16* W1p = (__bf16*)d_ws;                    // 32768 elems (65536 B)
  __bf16* W2p = W1p + 32768;                      // 16384 elems (32768 B)
  __bf16* Sp  = W2p + 16384;                      //  8192 elems (16384 B)
  float*  b1a  = (float*)((char*)d_ws + 114688);  // 256 f32
  float*  binv = b1a + 256;                       // 256 f32
  float*  badd = binv + 256;                      // 256 f32

  prep_pack<<<129, 256, 0, stream>>>(W1, W2, topo, spat, b1,
                                     bn0g, bn0b, bn0m, bn0v,
                                     bn1g, bn1b, bn1m, bn1v,
                                     bn2g, bn2b, bn2m, bn2v,
                                     W1p, W2p, Sp, b1a, binv, badd);
  fused_v16<<<2048, 512, 0, stream>>>(
      x, b2, W1p, W2p, Sp, b1a, binv, badd, out);
}